// Round 12
// baseline (1656.251 us; speedup 1.0000x reference)
//
#include <hip/hip_runtime.h>

// LSTM: L=2, B=32, T=256, N=M=1024, gates 4M=4096
// R12 = R11 + act-head x-GEMM under h-load flight:
//  act: issue 16 h bypass loads -> zero acc -> x-GEMM (64 MFMA on resident
//  bufX, hides the h round trip) -> h land+GEMM groups (vmcnt ~satisfied) ->
//  x/seq(t+1) prefetch issue -> gred -> S3 -> reduce/cell -> scatter store +
//  parallel drain -> S4 -> flag. Tail = pure 16-ds_write landing into bufX.
//  Enabler: gred COLUMN-aliased into bufH (wave w's partials in its own
//  [w*512,+512) col window, rows 0..15, XOR (n&7)<<4) -> wave-local writes,
//  no extra barrier vs R11. Strict 128-flag lockstep unchanged.

typedef __bf16 bf16x8 __attribute__((ext_vector_type(8)));
typedef float  f32x4  __attribute__((ext_vector_type(4)));
typedef unsigned u32x4 __attribute__((ext_vector_type(4)));

__device__ __forceinline__ unsigned short f2bf(float f) {
    union { float f; unsigned u; } v; v.f = f;
    unsigned u = v.u;
    unsigned r = u + 0x7fffu + ((u >> 16) & 1u);   // RNE
    return (unsigned short)(r >> 16);
}
__device__ __forceinline__ float sigmoidf_fast(float x) {
    return 1.0f / (1.0f + __expf(-x));
}
__device__ __forceinline__ float tanhf_fast(float x) {
    return 1.0f - 2.0f / (__expf(2.0f * x) + 1.0f);
}

// src: (L*4096, 1024) f32 -> dst: (L*4096, 2048) bf16 at column offset `off`
__global__ void cvt_w_concat(const float* __restrict__ src,
                             unsigned short* __restrict__ dst, int off, int n4) {
    int i = blockIdx.x * blockDim.x + threadIdx.x;
    int stride = gridDim.x * blockDim.x;
    for (; i < n4; i += stride) {
        float4 v = ((const float4*)src)[i];
        ushort4 o;
        o.x = f2bf(v.x); o.y = f2bf(v.y); o.z = f2bf(v.z); o.w = f2bf(v.w);
        int row = i >> 8;
        int c4  = i & 255;
        *(ushort4*)&dst[(size_t)row * 2048 + off + c4 * 4] = o;
    }
}

// x (B,T,N) f32 -> per-t tiles [t][blk 64][b 32][mi 16] bf16; one block per t
__global__ void cvt_x_tiles(const float* __restrict__ x,
                            unsigned short* __restrict__ xT) {
    int t = blockIdx.x, tid = threadIdx.x;
    unsigned short* tile = xT + (size_t)t * 32768;
    for (int b = 0; b < 32; ++b) {
        float4 v = *(const float4*)&x[((size_t)b * 256 + t) * 1024 + tid * 4];
        ushort4 o;
        o.x = f2bf(v.x); o.y = f2bf(v.y); o.z = f2bf(v.z); o.w = f2bf(v.w);
        *(ushort4*)&tile[(tid >> 2) * 512 + b * 16 + (tid & 3) * 4] = o;
    }
}

// h0 (L,B,M) f32 -> tiles [l][blk][b][mi] bf16; one block per l
__global__ void cvt_h0_tiles(const float* __restrict__ h0,
                             unsigned short* __restrict__ h0T) {
    int l = blockIdx.x, tid = threadIdx.x;
    unsigned short* tile = h0T + (size_t)l * 32768;
    for (int b = 0; b < 32; ++b) {
        float4 v = *(const float4*)&h0[((size_t)l * 32 + b) * 1024 + tid * 4];
        ushort4 o;
        o.x = f2bf(v.x); o.y = f2bf(v.y); o.z = f2bf(v.z); o.w = f2bf(v.w);
        *(ushort4*)&tile[(tid >> 2) * 512 + b * 16 + (tid & 3) * 4] = o;
    }
}

// outT [t][blk][b][mi] f32 -> out (B,T,M) f32; one block per t
__global__ void out_transpose(const float* __restrict__ outT,
                              float* __restrict__ out) {
    int t = blockIdx.x, tid = threadIdx.x;
    const float* tile = outT + (size_t)t * 32768;
    for (int b = 0; b < 32; ++b) {
        float4 v = *(const float4*)&tile[(tid >> 2) * 512 + b * 16 + (tid & 3) * 4];
        *(float4*)&out[((size_t)b * 256 + t) * 1024 + tid * 4] = v;
    }
}

__device__ __forceinline__ void pollge(const unsigned* fp, unsigned tgt) {
    while (true) {
        unsigned v = __hip_atomic_load(fp, __ATOMIC_RELAXED,
                                       __HIP_MEMORY_SCOPE_AGENT);
        if (__all((int)(v >= tgt))) break;
        __builtin_amdgcn_s_sleep(1);
    }
}

__global__ __launch_bounds__(256, 1) void lstm_fused(
    const unsigned short* __restrict__ Wcat,  // (L,4096,2048) bf16 [Wih|Whh]
    const unsigned short* __restrict__ xT,    // 256 x 64KB tiles bf16
    unsigned short* __restrict__ seqT,        // 256 x 64KB tiles (layer0 h)
    const unsigned short* __restrict__ h0T,   // 2 x 64KB tiles
    unsigned short* __restrict__ hparT,       // 2 x 64KB tiles (layer1 parity)
    float* __restrict__ outT,                 // 256 x 128KB f32 tiles
    const float* __restrict__ c0,             // (L,32,1024) f32
    const float* __restrict__ bih, const float* __restrict__ bhh,
    float* __restrict__ out, unsigned int* flags)   // flags: [2][64] u32 packed
{
    __shared__ __align__(16) unsigned short bufH[32][1024];  // 64KB h (gred alias)
    __shared__ __align__(16) unsigned short bufX[32][1024];  // 64KB x/seq

    const int tid  = threadIdx.x;
    const int lane = tid & 63;
    const int w    = tid >> 6;
    const int l    = blockIdx.x >> 6;
    const int bidl = blockIdx.x & 63;
    const int m0   = bidl * 16;
    const int n    = lane & 15;
    const int g    = lane >> 4;
    const int lk   = g * 8;
    const int nn7  = n & 7;

    char* const bH = (char*)&bufH[0][0];
    char* const bX = (char*)&bufX[0][0];

    // ---- persistent weights: wave w owns K-window [w*256,+256) in each half
    bf16x8 wx[32], wh[32];
    const unsigned short* Wl = Wcat + (size_t)l * 4096 * 2048;
    #pragma unroll
    for (int ct = 0; ct < 4; ct++) {
        int vc = ct * 16 + n;
        size_t jrow = (size_t)((vc & 3) * 1024 + m0 + (vc >> 2));
        #pragma unroll
        for (int kc = 0; kc < 8; kc++) {
            wx[ct*8+kc] = *(const bf16x8*)&Wl[jrow*2048 +        w*256 + kc*32 + lk];
            wh[ct*8+kc] = *(const bf16x8*)&Wl[jrow*2048 + 1024 + w*256 + kc*32 + lk];
        }
    }

    // ---- epilogue ownership: thread -> (batch eb, m-pair em,em+1)
    const int eb = lane >> 1;
    const int q  = lane & 1;
    const int em = m0 + 4 * w + 2 * q;
    float bs0[4], bs1[4];
    #pragma unroll
    for (int gg = 0; gg < 4; gg++) {
        bs0[gg] = bih[l*4096 + gg*1024 + em]     + bhh[l*4096 + gg*1024 + em];
        bs1[gg] = bih[l*4096 + gg*1024 + em + 1] + bhh[l*4096 + gg*1024 + em + 1];
    }
    float2 creg = *(const float2*)&c0[(size_t)l * 32768 + eb * 1024 + em];
    float2 hlast = {0.f, 0.f};
    const int uh = eb >> 4, urow = eb & 15;

    // ---- direct exchange-store offsets
    const int exOff  = bidl * 1024 + eb * 32 + (4 * w + 2 * q) * 2;
    const int outOff = bidl * 2048 + eb * 64 + (4 * w + 2 * q) * 4;

    // ---- wave-local staging: chunk si -> blk=w*16+si; lane -> (sb, halfk)
    const int sb     = lane >> 1;
    const int halfk  = lane & 1;
    const int srcOff = w * 16384 + sb * 32 + halfk * 16;
    const int sbRow  = sb * 2048;
    const int ldsCol = w * 512 + halfk * 16;
    const int swz    = (sb & 7) << 4;

    // ---- frag reads: phys = r*2048 + ((w*512+kc*64+g*16) ^ ((r&7)<<4))
    const int hb64 = (nn7 >> 2) * 64;
    const int gx16 = (g ^ (nn7 & 3)) * 16;
    const int rOffA0 = n * 2048 + w * 512 + gx16 + hb64;        // even kc
    const int rOffA1 = n * 2048 + w * 512 + gx16 + (64 - hb64); // odd  kc

    // ---- gred column-alias into bufH: wave w window = cols [w*512,+512),
    // rows 0..15. wb(h,ct,nn,r) = ((h*4+ct)*16+nn)*64 + r*4; byte =
    // ((wb>>9)<<11) + w*512 + ((wb&511) ^ ((nn&7)<<4)).
    const int nsw = (n & 7) << 4;

    f32x4 acc0[4], acc1[4];
    u32x4 hv[16];

    auto issue = [&](const char* tb, bool byp) {
        const char* gp = tb + srcOff;
        if (byp) {
            #pragma unroll
            for (int si = 0; si < 16; si++)
                asm volatile("global_load_dwordx4 %0, %1, off sc0 sc1"
                             : "=v"(hv[si]) : "v"(gp + si * 1024) : "memory");
        } else {
            #pragma unroll
            for (int si = 0; si < 16; si++)
                asm volatile("global_load_dwordx4 %0, %1, off"
                             : "=v"(hv[si]) : "v"(gp + si * 1024) : "memory");
        }
    };

    auto xgemm = [&]() {   // 64 MFMA on resident bufX (own column window)
        const char* pA0 = bX + rOffA0;
        const char* pA1 = bX + rOffA1;
        const char* pB0 = pA0 + 16 * 2048;
        const char* pB1 = pA1 + 16 * 2048;
        #pragma unroll
        for (int kc2 = 0; kc2 < 4; kc2++) {
            bf16x8 a0 = *(const bf16x8*)(pA0 + kc2 * 128);
            bf16x8 a1 = *(const bf16x8*)(pB0 + kc2 * 128);
            #pragma unroll
            for (int ct = 0; ct < 4; ct++) {
                acc0[ct] = __builtin_amdgcn_mfma_f32_16x16x32_bf16(a0, wx[ct*8+2*kc2],   acc0[ct],0,0,0);
                acc1[ct] = __builtin_amdgcn_mfma_f32_16x16x32_bf16(a1, wx[ct*8+2*kc2],   acc1[ct],0,0,0);
            }
            bf16x8 b0 = *(const bf16x8*)(pA1 + kc2 * 128);
            bf16x8 b1 = *(const bf16x8*)(pB1 + kc2 * 128);
            #pragma unroll
            for (int ct = 0; ct < 4; ct++) {
                acc0[ct] = __builtin_amdgcn_mfma_f32_16x16x32_bf16(b0, wx[ct*8+2*kc2+1], acc0[ct],0,0,0);
                acc1[ct] = __builtin_amdgcn_mfma_f32_16x16x32_bf16(b1, wx[ct*8+2*kc2+1], acc1[ct],0,0,0);
            }
        }
    };

    // ---- prologue: layer-0 lands x(0) into bufX (no gemm)
    if (l == 0) {
        issue((const char*)xT, false);
        asm volatile("s_waitcnt vmcnt(0)" ::: "memory");
        #pragma unroll
        for (int si = 0; si < 16; si++)
            *(u32x4*)(bX + sbRow + ((ldsCol + si * 32) ^ swz)) = hv[si];
    }
    __syncthreads();

    const int lag = l * 2;
    #pragma unroll 1
    for (int s = 0; s < 258; s++) {
        const int  t    = s - lag;
        const bool act  = (t >= 0) && (t < 256);
        const int  tn   = t + 1;
        const bool xact = (tn >= ((l == 0) ? 1 : 0)) && (tn <= 255);
        const char* xsrc = (l == 0) ? (const char*)(xT   + (size_t)tn * 32768)
                                    : (const char*)(seqT + (size_t)tn * 32768);

        if (act) {
            // ---- issue h(t-1) bypass loads (licensed by last poll)
            const char* hb = (t == 0)
                ? (const char*)(h0T + (size_t)l * 32768)
                : (l == 0 ? (const char*)(seqT + (size_t)(t - 1) * 32768)
                          : (const char*)(hparT + (size_t)((t - 1) & 1) * 32768));
            {
                const char* gp = hb + srcOff;
                #pragma unroll
                for (int si = 0; si < 16; si++)
                    asm volatile("global_load_dwordx4 %0, %1, off sc0 sc1"
                                 : "=v"(hv[si]) : "v"(gp + si * 1024) : "memory");
            }

            // ---- x-GEMM on resident bufX hides the h round trip
            #pragma unroll
            for (int ct = 0; ct < 4; ct++) {
                acc0[ct] = (f32x4){0.f, 0.f, 0.f, 0.f};
                acc1[ct] = (f32x4){0.f, 0.f, 0.f, 0.f};
            }
            xgemm();

            // ---- h land + GEMM groups (waits ~satisfied by now)
            {
                const char* pA0 = bH + rOffA0;
                const char* pA1 = bH + rOffA1;
                const char* pB0 = pA0 + 16 * 2048;
                const char* pB1 = pA1 + 16 * 2048;
#define SGRP(G4, VM) \
                asm volatile("s_waitcnt vmcnt(" VM ")" ::: "memory"); \
                _Pragma("unroll") \
                for (int si = 4*(G4); si < 4*(G4)+4; si++) \
                    *(u32x4*)(bH + sbRow + ((ldsCol + si*32) ^ swz)) = hv[si]; \
                { \
                    bf16x8 a0 = *(const bf16x8*)(pA0 + (G4)*128); \
                    bf16x8 a1 = *(const bf16x8*)(pB0 + (G4)*128); \
                    _Pragma("unroll") \
                    for (int ct = 0; ct < 4; ct++) { \
                        acc0[ct] = __builtin_amdgcn_mfma_f32_16x16x32_bf16(a0, wh[ct*8+2*(G4)],   acc0[ct],0,0,0); \
                        acc1[ct] = __builtin_amdgcn_mfma_f32_16x16x32_bf16(a1, wh[ct*8+2*(G4)],   acc1[ct],0,0,0); \
                    } \
                    bf16x8 b0 = *(const bf16x8*)(pA1 + (G4)*128); \
                    bf16x8 b1 = *(const bf16x8*)(pB1 + (G4)*128); \
                    _Pragma("unroll") \
                    for (int ct = 0; ct < 4; ct++) { \
                        acc0[ct] = __builtin_amdgcn_mfma_f32_16x16x32_bf16(b0, wh[ct*8+2*(G4)+1], acc0[ct],0,0,0); \
                        acc1[ct] = __builtin_amdgcn_mfma_f32_16x16x32_bf16(b1, wh[ct*8+2*(G4)+1], acc1[ct],0,0,0); \
                    } \
                }
                SGRP(0, "12") SGRP(1, "8") SGRP(2, "4") SGRP(3, "0")
#undef SGRP
            }

            // ---- prefetch x/seq(t+1); flight covers gred..store drain
            if (xact) issue(xsrc, l == 1);

            // ---- K-partials -> gred (bufH column window, wave-local)
            #pragma unroll
            for (int ct = 0; ct < 4; ct++) {
                int wb0 = ((0 * 4 + ct) * 16 + n) * 64 + g * 16;
                int wb1 = ((1 * 4 + ct) * 16 + n) * 64 + g * 16;
                *(f32x4*)(bH + ((wb0 >> 9) << 11) + w * 512 + ((wb0 & 511) ^ nsw)) = acc0[ct];
                *(f32x4*)(bH + ((wb1 >> 9) << 11) + w * 512 + ((wb1 & 511) ^ nsw)) = acc1[ct];
            }
            __syncthreads();                                  // S3
            // ---- reduce 4 partials + cell (thread: half uh, ct=w, n=8q+j)
            float g8[8];
            #pragma unroll
            for (int j = 0; j < 8; j++) {
                int nn  = 8 * q + j;
                int wbr = ((uh * 4 + w) * 16 + nn) * 64 + urow * 4;
                int rowb = (wbr >> 9) << 11;
                int colb = (wbr & 511) ^ ((nn & 7) << 4);
                g8[j] = (*(const float*)(bH + rowb + 0 * 512 + colb)
                       + *(const float*)(bH + rowb + 1 * 512 + colb))
                      + (*(const float*)(bH + rowb + 2 * 512 + colb)
                       + *(const float*)(bH + rowb + 3 * 512 + colb));
            }
            float gi0 = g8[0] + bs0[0], gf0 = g8[1] + bs0[1];
            float gg0 = g8[2] + bs0[2], go0 = g8[3] + bs0[3];
            float gi1 = g8[4] + bs1[0], gf1 = g8[5] + bs1[1];
            float gg1 = g8[6] + bs1[2], go1 = g8[7] + bs1[3];

            float c0n = sigmoidf_fast(gf0) * creg.x + sigmoidf_fast(gi0) * tanhf_fast(gg0);
            float c1n = sigmoidf_fast(gf1) * creg.y + sigmoidf_fast(gi1) * tanhf_fast(gg1);
            float h0v = sigmoidf_fast(go0) * tanhf_fast(c0n);
            float h1v = sigmoidf_fast(go1) * tanhf_fast(c1n);
            creg.x = c0n; creg.y = c1n;
            hlast.x = h0v; hlast.y = h1v;

            // ---- direct per-thread exchange store + parallel drain
            unsigned hp = (unsigned)f2bf(h0v) | ((unsigned)f2bf(h1v) << 16);
            {
                char* dp = (l == 0)
                    ? (char*)(seqT  + (size_t)t * 32768)       + exOff
                    : (char*)(hparT + (size_t)(t & 1) * 32768) + exOff;
                asm volatile("global_store_dword %0, %1, off sc0 sc1"
                             :: "v"(dp), "v"(hp) : "memory");
                if (l == 1) {
                    float2 hv2 = {h0v, h1v};
                    *(float2*)((char*)outT + (size_t)t * 131072 + outOff) = hv2;
                }
                asm volatile("s_waitcnt vmcnt(0)" ::: "memory");
            }
            __syncthreads();                                  // S4: all drained
            if (tid == 0)
                __hip_atomic_store(flags + l * 64 + bidl, (unsigned)(s + 1),
                                   __ATOMIC_RELAXED, __HIP_MEMORY_SCOPE_AGENT);
        } else {
            if (tid == 0)
                __hip_atomic_store(flags + l * 64 + bidl, (unsigned)(s + 1),
                                   __ATOMIC_RELAXED, __HIP_MEMORY_SCOPE_AGENT);
            if (xact) issue(xsrc, l == 1);             // l1 s=1: seq(0)
        }

        // ---- tail: land prefetched tile into bufX (loads already drained
        // in act path; else path pays one RT once)
        if (xact) {
            asm volatile("s_waitcnt vmcnt(0)" ::: "memory");
            #pragma unroll
            for (int si = 0; si < 16; si++)
                *(u32x4*)(bX + sbRow + ((ldsCol + si * 32) ^ swz)) = hv[si];
        }

        // ---- strict global lockstep: all 128 flags >= s+1
        if (tid < 128) pollge(flags + tid, (unsigned)(s + 1));
        __syncthreads();                                      // S5
    }

    // ---- final states
    float* hF = out + (size_t)8192 * 1024 + (size_t)l * 32768;
    float* cF = out + (size_t)8192 * 1024 + 65536 + (size_t)l * 32768;
    float2 hf2 = {hlast.x, hlast.y};
    *(float2*)&hF[eb * 1024 + em] = hf2;
    float2 cf2 = {creg.x, creg.y};
    *(float2*)&cF[eb * 1024 + em] = cf2;
}

extern "C" void kernel_launch(void* const* d_in, const int* in_sizes, int n_in,
                              void* d_out, int out_size, void* d_ws, size_t ws_size,
                              hipStream_t stream)
{
    const float* x   = (const float*)d_in[0];
    const float* h0  = (const float*)d_in[1];
    const float* c0  = (const float*)d_in[2];
    const float* Wih = (const float*)d_in[3];
    const float* Whh = (const float*)d_in[4];
    const float* bih = (const float*)d_in[5];
    const float* bhh = (const float*)d_in[6];
    float* out = (float*)d_out;

    char* p = (char*)d_ws;
    unsigned short* xT    = (unsigned short*)p; p += (size_t)256 * 32768 * 2;      // 16 MB
    unsigned short* seqT  = (unsigned short*)p; p += (size_t)256 * 32768 * 2;      // 16 MB
    unsigned short* Wcat  = (unsigned short*)p; p += (size_t)2 * 4096 * 2048 * 2;  // 32 MB
    unsigned short* h0T   = (unsigned short*)p; p += (size_t)2 * 32768 * 2;        // 128 KB
    unsigned short* hparT = (unsigned short*)p; p += (size_t)2 * 32768 * 2;        // 128 KB
    float*          outT  = (float*)p;          p += (size_t)256 * 32768 * 4;      // 32 MB
    unsigned int*   flags = (unsigned int*)p;   p += 4096;

    hipMemsetAsync(flags, 0, 4096, stream);
    cvt_w_concat<<<1024, 256, 0, stream>>>(Wih, Wcat, 0,    2 * 4096 * 256);
    cvt_w_concat<<<1024, 256, 0, stream>>>(Whh, Wcat, 1024, 2 * 4096 * 256);
    cvt_x_tiles<<<256, 256, 0, stream>>>(x, xT);
    cvt_h0_tiles<<<2, 256, 0, stream>>>(h0, h0T);

    lstm_fused<<<128, 256, 0, stream>>>(Wcat, xT, seqT, h0T, hparT, outT,
                                        c0, bih, bhh, out, flags);

    out_transpose<<<256, 256, 0, stream>>>(outT, out);
}

// Round 13
// 1518.327 us; speedup vs baseline: 1.0908x; 1.0908x over previous
//
#include <hip/hip_runtime.h>

// LSTM: L=2, B=32, T=256, N=M=1024, gates 4M=4096
// R13 = R11 + two latency-shadow fixes (protocol identical to R11):
//  (1) x-GEMM split 32/32: head kc2{0,1} runs UNDER the h-load flight (free
//      if load-RT dominates); tail keeps kc2{2,3}+landing as post-flag poll
//      cover (R6/R12 lesson: pre-flag cycles are paid, post-flag are free).
//      Enabler: gred column-aliased into bufH (R12-verified); bufX unaliased.
//      acc carries tail -> next head (zeroed in tail/prologue only).
//  (2) store-THEN-prefetch + vmcnt(16): FIFO drains exactly the 1-2 exchange
//      stores while 16 prefetch loads stay in flight across a RAW s_barrier
//      S4 + flag + poll; tail TGRP counted waits land them (~free).

typedef __bf16 bf16x8 __attribute__((ext_vector_type(8)));
typedef float  f32x4  __attribute__((ext_vector_type(4)));
typedef unsigned u32x4 __attribute__((ext_vector_type(4)));

__device__ __forceinline__ unsigned short f2bf(float f) {
    union { float f; unsigned u; } v; v.f = f;
    unsigned u = v.u;
    unsigned r = u + 0x7fffu + ((u >> 16) & 1u);   // RNE
    return (unsigned short)(r >> 16);
}
__device__ __forceinline__ float sigmoidf_fast(float x) {
    return 1.0f / (1.0f + __expf(-x));
}
__device__ __forceinline__ float tanhf_fast(float x) {
    return 1.0f - 2.0f / (__expf(2.0f * x) + 1.0f);
}

// src: (L*4096, 1024) f32 -> dst: (L*4096, 2048) bf16 at column offset `off`
__global__ void cvt_w_concat(const float* __restrict__ src,
                             unsigned short* __restrict__ dst, int off, int n4) {
    int i = blockIdx.x * blockDim.x + threadIdx.x;
    int stride = gridDim.x * blockDim.x;
    for (; i < n4; i += stride) {
        float4 v = ((const float4*)src)[i];
        ushort4 o;
        o.x = f2bf(v.x); o.y = f2bf(v.y); o.z = f2bf(v.z); o.w = f2bf(v.w);
        int row = i >> 8;
        int c4  = i & 255;
        *(ushort4*)&dst[(size_t)row * 2048 + off + c4 * 4] = o;
    }
}

// x (B,T,N) f32 -> per-t tiles [t][blk 64][b 32][mi 16] bf16; one block per t
__global__ void cvt_x_tiles(const float* __restrict__ x,
                            unsigned short* __restrict__ xT) {
    int t = blockIdx.x, tid = threadIdx.x;
    unsigned short* tile = xT + (size_t)t * 32768;
    for (int b = 0; b < 32; ++b) {
        float4 v = *(const float4*)&x[((size_t)b * 256 + t) * 1024 + tid * 4];
        ushort4 o;
        o.x = f2bf(v.x); o.y = f2bf(v.y); o.z = f2bf(v.z); o.w = f2bf(v.w);
        *(ushort4*)&tile[(tid >> 2) * 512 + b * 16 + (tid & 3) * 4] = o;
    }
}

// h0 (L,B,M) f32 -> tiles [l][blk][b][mi] bf16; one block per l
__global__ void cvt_h0_tiles(const float* __restrict__ h0,
                             unsigned short* __restrict__ h0T) {
    int l = blockIdx.x, tid = threadIdx.x;
    unsigned short* tile = h0T + (size_t)l * 32768;
    for (int b = 0; b < 32; ++b) {
        float4 v = *(const float4*)&h0[((size_t)l * 32 + b) * 1024 + tid * 4];
        ushort4 o;
        o.x = f2bf(v.x); o.y = f2bf(v.y); o.z = f2bf(v.z); o.w = f2bf(v.w);
        *(ushort4*)&tile[(tid >> 2) * 512 + b * 16 + (tid & 3) * 4] = o;
    }
}

// outT [t][blk][b][mi] f32 -> out (B,T,M) f32; one block per t
__global__ void out_transpose(const float* __restrict__ outT,
                              float* __restrict__ out) {
    int t = blockIdx.x, tid = threadIdx.x;
    const float* tile = outT + (size_t)t * 32768;
    for (int b = 0; b < 32; ++b) {
        float4 v = *(const float4*)&tile[(tid >> 2) * 512 + b * 16 + (tid & 3) * 4];
        *(float4*)&out[((size_t)b * 256 + t) * 1024 + tid * 4] = v;
    }
}

__device__ __forceinline__ void pollge(const unsigned* fp, unsigned tgt) {
    while (true) {
        unsigned v = __hip_atomic_load(fp, __ATOMIC_RELAXED,
                                       __HIP_MEMORY_SCOPE_AGENT);
        if (__all((int)(v >= tgt))) break;
        __builtin_amdgcn_s_sleep(1);
    }
}

__global__ __launch_bounds__(256, 1) void lstm_fused(
    const unsigned short* __restrict__ Wcat,  // (L,4096,2048) bf16 [Wih|Whh]
    const unsigned short* __restrict__ xT,    // 256 x 64KB tiles bf16
    unsigned short* __restrict__ seqT,        // 256 x 64KB tiles (layer0 h)
    const unsigned short* __restrict__ h0T,   // 2 x 64KB tiles
    unsigned short* __restrict__ hparT,       // 2 x 64KB tiles (layer1 parity)
    float* __restrict__ outT,                 // 256 x 128KB f32 tiles
    const float* __restrict__ c0,             // (L,32,1024) f32
    const float* __restrict__ bih, const float* __restrict__ bhh,
    float* __restrict__ out, unsigned int* flags)   // flags: [2][64] u32 packed
{
    __shared__ __align__(16) unsigned short bufH[32][1024];  // 64KB h (gred cols)
    __shared__ __align__(16) unsigned short bufX[32][1024];  // 64KB x/seq

    const int tid  = threadIdx.x;
    const int lane = tid & 63;
    const int w    = tid >> 6;
    const int l    = blockIdx.x >> 6;
    const int bidl = blockIdx.x & 63;
    const int m0   = bidl * 16;
    const int n    = lane & 15;
    const int g    = lane >> 4;
    const int lk   = g * 8;
    const int nn7  = n & 7;

    char* const bH = (char*)&bufH[0][0];
    char* const bX = (char*)&bufX[0][0];

    // ---- persistent weights: wave w owns K-window [w*256,+256) in each half
    bf16x8 wx[32], wh[32];
    const unsigned short* Wl = Wcat + (size_t)l * 4096 * 2048;
    #pragma unroll
    for (int ct = 0; ct < 4; ct++) {
        int vc = ct * 16 + n;
        size_t jrow = (size_t)((vc & 3) * 1024 + m0 + (vc >> 2));
        #pragma unroll
        for (int kc = 0; kc < 8; kc++) {
            wx[ct*8+kc] = *(const bf16x8*)&Wl[jrow*2048 +        w*256 + kc*32 + lk];
            wh[ct*8+kc] = *(const bf16x8*)&Wl[jrow*2048 + 1024 + w*256 + kc*32 + lk];
        }
    }

    // ---- epilogue ownership: thread -> (batch eb, m-pair em,em+1)
    const int eb = lane >> 1;
    const int q  = lane & 1;
    const int em = m0 + 4 * w + 2 * q;
    float bs0[4], bs1[4];
    #pragma unroll
    for (int gg = 0; gg < 4; gg++) {
        bs0[gg] = bih[l*4096 + gg*1024 + em]     + bhh[l*4096 + gg*1024 + em];
        bs1[gg] = bih[l*4096 + gg*1024 + em + 1] + bhh[l*4096 + gg*1024 + em + 1];
    }
    float2 creg = *(const float2*)&c0[(size_t)l * 32768 + eb * 1024 + em];
    float2 hlast = {0.f, 0.f};
    const int uh = eb >> 4, urow = eb & 15;

    // ---- direct exchange-store offsets
    const int exOff  = bidl * 1024 + eb * 32 + (4 * w + 2 * q) * 2;
    const int outOff = bidl * 2048 + eb * 64 + (4 * w + 2 * q) * 4;

    // ---- wave-local staging: chunk si -> blk=w*16+si; lane -> (sb, halfk)
    const int sb     = lane >> 1;
    const int halfk  = lane & 1;
    const int srcOff = w * 16384 + sb * 32 + halfk * 16;
    const int sbRow  = sb * 2048;
    const int ldsCol = w * 512 + halfk * 16;
    const int swz    = (sb & 7) << 4;

    // ---- frag reads: phys = r*2048 + ((w*512+kc*64+g*16) ^ ((r&7)<<4))
    const int hb64 = (nn7 >> 2) * 64;
    const int gx16 = (g ^ (nn7 & 3)) * 16;
    const int rOffA0 = n * 2048 + w * 512 + gx16 + hb64;        // even kc
    const int rOffA1 = n * 2048 + w * 512 + gx16 + (64 - hb64); // odd  kc

    // ---- gred column-alias into bufH (R12-verified): wave w window =
    // cols [w*512,+512), rows 0..15. wb = ((h*4+ct)*16+nn)*64 + r*4.
    const int nsw = (n & 7) << 4;

    f32x4 acc0[4] = {}, acc1[4] = {};
    u32x4 hv[16];

    auto issue = [&](const char* tb, bool byp) {
        const char* gp = tb + srcOff;
        if (byp) {
            #pragma unroll
            for (int si = 0; si < 16; si++)
                asm volatile("global_load_dwordx4 %0, %1, off sc0 sc1"
                             : "=v"(hv[si]) : "v"(gp + si * 1024) : "memory");
        } else {
            #pragma unroll
            for (int si = 0; si < 16; si++)
                asm volatile("global_load_dwordx4 %0, %1, off"
                             : "=v"(hv[si]) : "v"(gp + si * 1024) : "memory");
        }
    };

    // one x k-group (8 MFMA pairs = 16 MFMA) on bufX, kc2 in [0,4)
#define XSTEP(KC2) { \
        const char* pA0 = bX + rOffA0; \
        const char* pA1 = bX + rOffA1; \
        const char* pB0 = pA0 + 16 * 2048; \
        const char* pB1 = pA1 + 16 * 2048; \
        bf16x8 a0 = *(const bf16x8*)(pA0 + (KC2)*128); \
        bf16x8 a1 = *(const bf16x8*)(pB0 + (KC2)*128); \
        _Pragma("unroll") \
        for (int ct = 0; ct < 4; ct++) { \
            acc0[ct] = __builtin_amdgcn_mfma_f32_16x16x32_bf16(a0, wx[ct*8+2*(KC2)],   acc0[ct],0,0,0); \
            acc1[ct] = __builtin_amdgcn_mfma_f32_16x16x32_bf16(a1, wx[ct*8+2*(KC2)],   acc1[ct],0,0,0); \
        } \
        bf16x8 b0 = *(const bf16x8*)(pA1 + (KC2)*128); \
        bf16x8 b1 = *(const bf16x8*)(pB1 + (KC2)*128); \
        _Pragma("unroll") \
        for (int ct = 0; ct < 4; ct++) { \
            acc0[ct] = __builtin_amdgcn_mfma_f32_16x16x32_bf16(b0, wx[ct*8+2*(KC2)+1], acc0[ct],0,0,0); \
            acc1[ct] = __builtin_amdgcn_mfma_f32_16x16x32_bf16(b1, wx[ct*8+2*(KC2)+1], acc1[ct],0,0,0); \
        } }

    // ---- prologue: layer-0 lands x(0), computes kc2{2,3} (tail-equivalent)
    if (l == 0) {
        issue((const char*)xT, false);
        asm volatile("s_waitcnt vmcnt(0)" ::: "memory");
        #pragma unroll
        for (int si = 0; si < 16; si++)
            *(u32x4*)(bX + sbRow + ((ldsCol + si * 32) ^ swz)) = hv[si];
        XSTEP(2) XSTEP(3)
    }
    __syncthreads();

    const int lag = l * 2;
    #pragma unroll 1
    for (int s = 0; s < 258; s++) {
        const int  t    = s - lag;
        const bool act  = (t >= 0) && (t < 256);
        const int  tn   = t + 1;
        const bool xact = (tn >= ((l == 0) ? 1 : 0)) && (tn <= 255);
        const char* xsrc = (l == 0) ? (const char*)(xT   + (size_t)tn * 32768)
                                    : (const char*)(seqT + (size_t)tn * 32768);

        if (act) {
            // ---- issue h(t-1) bypass loads (licensed by last poll)
            const char* hb = (t == 0)
                ? (const char*)(h0T + (size_t)l * 32768)
                : (l == 0 ? (const char*)(seqT + (size_t)(t - 1) * 32768)
                          : (const char*)(hparT + (size_t)((t - 1) & 1) * 32768));
            {
                const char* gp = hb + srcOff;
                #pragma unroll
                for (int si = 0; si < 16; si++)
                    asm volatile("global_load_dwordx4 %0, %1, off sc0 sc1"
                                 : "=v"(hv[si]) : "v"(gp + si * 1024) : "memory");
            }

            // ---- head x-GEMM kc2{0,1}: free under the h-load flight
            XSTEP(0) XSTEP(1)

            // ---- h land + GEMM groups
            {
                const char* pA0 = bH + rOffA0;
                const char* pA1 = bH + rOffA1;
                const char* pB0 = pA0 + 16 * 2048;
                const char* pB1 = pA1 + 16 * 2048;
#define SGRP(G4, VM) \
                asm volatile("s_waitcnt vmcnt(" VM ")" ::: "memory"); \
                _Pragma("unroll") \
                for (int si = 4*(G4); si < 4*(G4)+4; si++) \
                    *(u32x4*)(bH + sbRow + ((ldsCol + si*32) ^ swz)) = hv[si]; \
                { \
                    bf16x8 a0 = *(const bf16x8*)(pA0 + (G4)*128); \
                    bf16x8 a1 = *(const bf16x8*)(pB0 + (G4)*128); \
                    _Pragma("unroll") \
                    for (int ct = 0; ct < 4; ct++) { \
                        acc0[ct] = __builtin_amdgcn_mfma_f32_16x16x32_bf16(a0, wh[ct*8+2*(G4)],   acc0[ct],0,0,0); \
                        acc1[ct] = __builtin_amdgcn_mfma_f32_16x16x32_bf16(a1, wh[ct*8+2*(G4)],   acc1[ct],0,0,0); \
                    } \
                    bf16x8 b0 = *(const bf16x8*)(pA1 + (G4)*128); \
                    bf16x8 b1 = *(const bf16x8*)(pB1 + (G4)*128); \
                    _Pragma("unroll") \
                    for (int ct = 0; ct < 4; ct++) { \
                        acc0[ct] = __builtin_amdgcn_mfma_f32_16x16x32_bf16(b0, wh[ct*8+2*(G4)+1], acc0[ct],0,0,0); \
                        acc1[ct] = __builtin_amdgcn_mfma_f32_16x16x32_bf16(b1, wh[ct*8+2*(G4)+1], acc1[ct],0,0,0); \
                    } \
                }
                SGRP(0, "12") SGRP(1, "8") SGRP(2, "4") SGRP(3, "0")
#undef SGRP
            }

            // ---- K-partials -> gred (bufH column window, wave-local)
            #pragma unroll
            for (int ct = 0; ct < 4; ct++) {
                int wb0 = ((0 * 4 + ct) * 16 + n) * 64 + g * 16;
                int wb1 = ((1 * 4 + ct) * 16 + n) * 64 + g * 16;
                *(f32x4*)(bH + ((wb0 >> 9) << 11) + w * 512 + ((wb0 & 511) ^ nsw)) = acc0[ct];
                *(f32x4*)(bH + ((wb1 >> 9) << 11) + w * 512 + ((wb1 & 511) ^ nsw)) = acc1[ct];
            }
            __syncthreads();                                  // S3
            // ---- reduce 4 partials + cell (thread: half uh, ct=w, n=8q+j)
            float g8[8];
            #pragma unroll
            for (int j = 0; j < 8; j++) {
                int nn  = 8 * q + j;
                int wbr = ((uh * 4 + w) * 16 + nn) * 64 + urow * 4;
                int rowb = (wbr >> 9) << 11;
                int colb = (wbr & 511) ^ ((nn & 7) << 4);
                g8[j] = (*(const float*)(bH + rowb + 0 * 512 + colb)
                       + *(const float*)(bH + rowb + 1 * 512 + colb))
                      + (*(const float*)(bH + rowb + 2 * 512 + colb)
                       + *(const float*)(bH + rowb + 3 * 512 + colb));
            }
            float gi0 = g8[0] + bs0[0], gf0 = g8[1] + bs0[1];
            float gg0 = g8[2] + bs0[2], go0 = g8[3] + bs0[3];
            float gi1 = g8[4] + bs1[0], gf1 = g8[5] + bs1[1];
            float gg1 = g8[6] + bs1[2], go1 = g8[7] + bs1[3];

            float c0n = sigmoidf_fast(gf0) * creg.x + sigmoidf_fast(gi0) * tanhf_fast(gg0);
            float c1n = sigmoidf_fast(gf1) * creg.y + sigmoidf_fast(gi1) * tanhf_fast(gg1);
            float h0v = sigmoidf_fast(go0) * tanhf_fast(c0n);
            float h1v = sigmoidf_fast(go1) * tanhf_fast(c1n);
            creg.x = c0n; creg.y = c1n;
            hlast.x = h0v; hlast.y = h1v;

            // ---- exchange store FIRST, then prefetch, then counted drain:
            // vmcnt(16) drains exactly the stores; 16 loads stay in flight
            unsigned hp = (unsigned)f2bf(h0v) | ((unsigned)f2bf(h1v) << 16);
            {
                char* dp = (l == 0)
                    ? (char*)(seqT  + (size_t)t * 32768)       + exOff
                    : (char*)(hparT + (size_t)(t & 1) * 32768) + exOff;
                asm volatile("global_store_dword %0, %1, off sc0 sc1"
                             :: "v"(dp), "v"(hp) : "memory");
                if (l == 1) {
                    float2 hv2 = {h0v, h1v};
                    *(float2*)((char*)outT + (size_t)t * 131072 + outOff) = hv2;
                }
            }
            if (xact) {
                issue(xsrc, l == 1);
                asm volatile("s_waitcnt vmcnt(16)" ::: "memory");
            } else {
                asm volatile("s_waitcnt vmcnt(0)" ::: "memory");
            }
            // raw S4: gather waves without draining the prefetch
            asm volatile("s_waitcnt lgkmcnt(0)" ::: "memory");
            __builtin_amdgcn_s_barrier();
            __builtin_amdgcn_sched_barrier(0);
            if (tid == 0)
                __hip_atomic_store(flags + l * 64 + bidl, (unsigned)(s + 1),
                                   __ATOMIC_RELAXED, __HIP_MEMORY_SCOPE_AGENT);
        } else {
            if (tid == 0)
                __hip_atomic_store(flags + l * 64 + bidl, (unsigned)(s + 1),
                                   __ATOMIC_RELAXED, __HIP_MEMORY_SCOPE_AGENT);
            if (xact) issue(xsrc, l == 1);             // l1 s=1: seq(0)
        }

        // ---- tail: land all 16 chunks + x-GEMM kc2{2,3} (post-flag cover)
        if (xact) {
            #pragma unroll
            for (int ct = 0; ct < 4; ct++) {
                acc0[ct] = (f32x4){0.f, 0.f, 0.f, 0.f};
                acc1[ct] = (f32x4){0.f, 0.f, 0.f, 0.f};
            }
#define TLND(G4, VM) \
            asm volatile("s_waitcnt vmcnt(" VM ")" ::: "memory"); \
            _Pragma("unroll") \
            for (int si = 4*(G4); si < 4*(G4)+4; si++) \
                *(u32x4*)(bX + sbRow + ((ldsCol + si*32) ^ swz)) = hv[si];
            TLND(0, "12") TLND(1, "8")
            TLND(2, "4")  XSTEP(2)
            TLND(3, "0")  XSTEP(3)
#undef TLND
        }

        // ---- strict global lockstep: all 128 flags >= s+1
        if (tid < 128) pollge(flags + tid, (unsigned)(s + 1));
        __syncthreads();                                      // S5
    }

    // ---- final states
    float* hF = out + (size_t)8192 * 1024 + (size_t)l * 32768;
    float* cF = out + (size_t)8192 * 1024 + 65536 + (size_t)l * 32768;
    float2 hf2 = {hlast.x, hlast.y};
    *(float2*)&hF[eb * 1024 + em] = hf2;
    float2 cf2 = {creg.x, creg.y};
    *(float2*)&cF[eb * 1024 + em] = cf2;
}

extern "C" void kernel_launch(void* const* d_in, const int* in_sizes, int n_in,
                              void* d_out, int out_size, void* d_ws, size_t ws_size,
                              hipStream_t stream)
{
    const float* x   = (const float*)d_in[0];
    const float* h0  = (const float*)d_in[1];
    const float* c0  = (const float*)d_in[2];
    const float* Wih = (const float*)d_in[3];
    const float* Whh = (const float*)d_in[4];
    const float* bih = (const float*)d_in[5];
    const float* bhh = (const float*)d_in[6];
    float* out = (float*)d_out;

    char* p = (char*)d_ws;
    unsigned short* xT    = (unsigned short*)p; p += (size_t)256 * 32768 * 2;      // 16 MB
    unsigned short* seqT  = (unsigned short*)p; p += (size_t)256 * 32768 * 2;      // 16 MB
    unsigned short* Wcat  = (unsigned short*)p; p += (size_t)2 * 4096 * 2048 * 2;  // 32 MB
    unsigned short* h0T   = (unsigned short*)p; p += (size_t)2 * 32768 * 2;        // 128 KB
    unsigned short* hparT = (unsigned short*)p; p += (size_t)2 * 32768 * 2;        // 128 KB
    float*          outT  = (float*)p;          p += (size_t)256 * 32768 * 4;      // 32 MB
    unsigned int*   flags = (unsigned int*)p;   p += 4096;

    hipMemsetAsync(flags, 0, 4096, stream);
    cvt_w_concat<<<1024, 256, 0, stream>>>(Wih, Wcat, 0,    2 * 4096 * 256);
    cvt_w_concat<<<1024, 256, 0, stream>>>(Whh, Wcat, 1024, 2 * 4096 * 256);
    cvt_x_tiles<<<256, 256, 0, stream>>>(x, xT);
    cvt_h0_tiles<<<2, 256, 0, stream>>>(h0, h0T);

    lstm_fused<<<128, 256, 0, stream>>>(Wcat, xT, seqT, h0T, hparT, outT,
                                        c0, bih, bhh, out, flags);

    out_transpose<<<256, 256, 0, stream>>>(outT, out);
}